// Round 14
// baseline (66.068 us; speedup 1.0000x reference)
//
#include <hip/hip_runtime.h>
#include <math.h>

#define NB 8
#define NT 4096
#define ND 1024
#define NL 3
#define NO 4
#define NLO 12
#define NROWS (NB * NT)          // 32768
#define TWO_PI_D 6.283185307179586476925286766559
#define DT_D 0.1
#define NSTEPS 10
#define THRESH_D 0.3

typedef double f64x4 __attribute__((ext_vector_type(4)));

// ------------- Kernel W-prep: W[12][1024] f32 -> Wt[1024][16] f64 (padded) --
__global__ __launch_bounds__(256) void k_wprep(const float* __restrict__ W,
                                               double* __restrict__ wsWt)
{
    int i = blockIdx.x * 256 + threadIdx.x;   // 0..16383
    if (i < 1024 * 16) {
        int k = i >> 4, col = i & 15;
        wsWt[i] = (col < NLO) ? (double)W[col * ND + k] : 0.0;
    }
}

// ------------- Kernel A v14: f64 MFMA GEMM, depth-2 register pipeline -------
// v13 structure (1024 blk x 4 waves, 2 row-tiles/wave, B amortized) with the
// pipeline deepened to 2: x loads issued 2 ss ahead (~1400 cyc to land),
// B loads 1 ss ahead (L2 ~200 cyc), ds_write's vmcnt wait is on loads issued
// a full period ago (~0 stall). Only remaining per-ss wait: lgkmcnt on 8
// conflict-free ds_read_b32. setprio around the MFMA cluster (independent
// waves). All pipeline state in named regs / constant-index arrays.
__global__ __launch_bounds__(256, 4) void k_proj(
    const float* __restrict__ x, const double* __restrict__ wsWt,
    double* __restrict__ ws_proj)
{
    __shared__ char buf[20480];                   // 4 waves x 2 halves x 32x20 f32
    const int tid  = threadIdx.x;
    const int lane = tid & 63;
    const int wid  = tid >> 6;                    // K-quarter 0..3
    const int m    = lane & 15;
    const int kk   = lane >> 4;                   // 0..3
    const long row0 = (long)blockIdx.x * 32;

    float* wtile = reinterpret_cast<float*>(buf) + wid * 1280;  // 2 halves x 640
    const int srow = lane >> 2;                   // staging row 0..15
    const int slot = lane & 3;
    const float* xg = x + (row0 + srow) * ND + wid * 256 + slot * 4;
    const double* wq = wsWt + (long)(wid * 256) * 16;

    f64x4 accA = {0.0, 0.0, 0.0, 0.0};
    f64x4 accB = {0.0, 0.0, 0.0, 0.0};

    // pipeline regs
    float4 frwA, frwB;        // x data for ss+1 (to ds_write this iter)
    float4 frlA, frlB;        // x data for ss+2 (being loaded)
    double bv[4], bn[4];      // B frags: current ss / next ss

    // prologue: x(0) -> half0; frw = x(1); bv = B(0)
    {
        float4 f0A = *reinterpret_cast<const float4*>(xg);
        float4 f0B = *reinterpret_cast<const float4*>(xg + 16 * ND);
        frwA = *reinterpret_cast<const float4*>(xg + 16);
        frwB = *reinterpret_cast<const float4*>(xg + 16 * ND + 16);
#pragma unroll
        for (int p = 0; p < 4; ++p) bv[p] = wq[(4 * p + kk) * 16 + m];
        *reinterpret_cast<float4*>(&wtile[srow * 20 + slot * 4]) = f0A;
        *reinterpret_cast<float4*>(&wtile[(16 + srow) * 20 + slot * 4]) = f0B;
    }

#pragma unroll 2
    for (int ss = 0; ss < 16; ++ss) {
        float* cur = wtile + (ss & 1) * 640;
        float* nxt = wtile + ((ss + 1) & 1) * 640;
        // (1) write x(ss+1) — issued a full period ago, near-zero vmcnt wait
        if (ss < 15) {
            *reinterpret_cast<float4*>(&nxt[srow * 20 + slot * 4]) = frwA;
            *reinterpret_cast<float4*>(&nxt[(16 + srow) * 20 + slot * 4]) = frwB;
        }
        // (2) issue x(ss+2)
        if (ss < 14) {
            frlA = *reinterpret_cast<const float4*>(xg + 16 * (ss + 2));
            frlB = *reinterpret_cast<const float4*>(xg + 16 * ND + 16 * (ss + 2));
        }
        // (3) issue B(ss+1)
        if (ss < 15) {
#pragma unroll
            for (int p = 0; p < 4; ++p)
                bn[p] = wq[(16 * (ss + 1) + 4 * p + kk) * 16 + m];
        }
        // (4) A frags from current half (2 lanes/bank = free) + 8 MFMA
        __builtin_amdgcn_s_setprio(1);
#pragma unroll
        for (int p = 0; p < 4; ++p) {
            double aA = (double)cur[m * 20 + 4 * p + kk];
            double aB = (double)cur[(16 + m) * 20 + 4 * p + kk];
            accA = __builtin_amdgcn_mfma_f64_16x16x4f64(aA, bv[p], accA, 0, 0, 0);
            accB = __builtin_amdgcn_mfma_f64_16x16x4f64(aB, bv[p], accB, 0, 0, 0);
        }
        __builtin_amdgcn_s_setprio(0);
        // (5) rotate pipeline regs (pure renames after unroll)
        frwA = frlA; frwB = frlB;
#pragma unroll
        for (int p = 0; p < 4; ++p) bv[p] = bn[p];
    }

    // inline C/D layout probe (separable inputs; same feed convention)
    f64x4 z = {0.0, 0.0, 0.0, 0.0};
    f64x4 d1 = __builtin_amdgcn_mfma_f64_16x16x4f64((double)m, 1.0, z, 0, 0, 0);
    f64x4 d2 = __builtin_amdgcn_mfma_f64_16x16x4f64(1.0, (double)m, z, 0, 0, 0);

    // 4-way K-fold through LDS (red overlays tiles; 16 KB <= 20 KB)
    __syncthreads();
    double* red = reinterpret_cast<double*>(buf);
#pragma unroll
    for (int n = 0; n < 4; ++n)
        red[((wid * 2 + 0) * 64 + lane) * 4 + n] = accA[n];
#pragma unroll
    for (int n = 0; n < 4; ++n)
        red[((wid * 2 + 1) * 64 + lane) * 4 + n] = accB[n];
    __syncthreads();

    if (wid < 2) {                                // thread folds tile t = wid
#pragma unroll
        for (int n = 0; n < 4; ++n) {
            double v = (red[((0 * 2 + wid) * 64 + lane) * 4 + n] +
                        red[((1 * 2 + wid) * 64 + lane) * 4 + n]) +
                       (red[((2 * 2 + wid) * 64 + lane) * 4 + n] +
                        red[((3 * 2 + wid) * 64 + lane) * 4 + n]);
            int i = (int)(d1[n] * 0.25 + 0.5);
            int j = (int)(d2[n] * 0.25 + 0.5);
            if (j < NLO)
                ws_proj[(long)j * NROWS + row0 + wid * 16 + i] = v;
        }
    }
}

// ------------- Kernel B v5: fused phase-init + 10 Kuramoto steps ------------
#define B_THREADS 512
#define B_ELEMS (NT / B_THREADS)   // 8

__global__ __launch_bounds__(B_THREADS) void k_kuramoto(
    const float* __restrict__ omegas, const float* __restrict__ Ks,
    const double* __restrict__ ws_proj, float* __restrict__ ws_s,
    float* __restrict__ ws_c, double* __restrict__ ws_r,
    float* __restrict__ out_ph)
{
    const int g = blockIdx.x;              // (l*NB + b)*NO + o
    const int l = g >> 5;
    const int b = (g >> 2) & 7;
    const int o = g & 3;
    const double om = (double)omegas[l * NO + o];
    const double Kv = (double)Ks[l];
    const double dtom = DT_D * om;
    const double cKT = DT_D * Kv / (double)NT;  // |eps| <= dt*K/T ~ 5e-5
    double sA, cA; sincos(dtom, &sA, &cA);
    const int tid = threadIdx.x;
    const int wid = tid >> 6;
    const int lane = tid & 63;
    __shared__ double lds[16];

    // fused phase init from proj columns (contiguous reads)
    const double* pA = ws_proj + (long)(l * NO + o) * NROWS + (long)b * NT;
    const double* pB = ws_proj + (long)(l * NO + ((o + 3) & 3)) * NROWS + (long)b * NT;

    double ph[B_ELEMS], s[B_ELEMS], c[B_ELEMS];
#pragma unroll
    for (int k = 0; k < B_ELEMS; ++k) {
        int t = tid + k * B_THREADS;
        double y = pA[t];
        double xx = pB[t] + 1e-8;
        double p = atan2(y, xx);
        if (p < 0.0) p += TWO_PI_D;
        ph[k] = p;
        double r2 = sqrt(y * y + xx * xx);
        if (r2 > 0.0) { s[k] = y / r2; c[k] = xx / r2; }
        else          { s[k] = 0.0;    c[k] = 1.0; }
    }

    for (int step = 0; step < NSTEPS; ++step) {
        double ts = 0.0, tc = 0.0;
#pragma unroll
        for (int k = 0; k < B_ELEMS; ++k) { ts += s[k]; tc += c[k]; }
#pragma unroll
        for (int off = 32; off > 0; off >>= 1) {
            ts += __shfl_down(ts, off);
            tc += __shfl_down(tc, off);
        }
        if (lane == 0) { lds[wid] = ts; lds[8 + wid] = tc; }
        __syncthreads();
        // every thread redundantly folds the 8 partials (no serial section)
        double S = 0.0, C = 0.0;
#pragma unroll
        for (int w = 0; w < 8; ++w) { S += lds[w]; C += lds[8 + w]; }
        double rr = sqrt(S * S + C * C);
        double sm, cm;
        if (rr > 0.0) { sm = S / rr; cm = C / rr; } else { sm = 0.0; cm = 1.0; }
#pragma unroll
        for (int k = 0; k < B_ELEMS; ++k) {
            double sv = sm * c[k] - cm * s[k];      // sin(mean - ph)
            double eps = cKT * sv;                  // |eps| <= ~5e-5
            double val = ph[k] + (dtom + eps);
            if (val >= TWO_PI_D) val -= TWO_PI_D;   // exact (Sterbenz)
            if (val < 0.0) val += TWO_PI_D;
            ph[k] = val;
            // rotate (s,c) by dtom+eps: sd = sA + cA*eps, cd = cA - sA*eps
            double sd = fma(cA, eps, sA);
            double cd = fma(-sA, eps, cA);
            double sn = fma(s[k], cd, c[k] * sd);
            double cn = fma(c[k], cd, -(s[k] * sd));
            s[k] = sn; c[k] = cn;
        }
        __syncthreads();               // protect lds before next step's writes
    }
    // level coherence from final s,c
    {
        double ts = 0.0, tc = 0.0;
#pragma unroll
        for (int k = 0; k < B_ELEMS; ++k) { ts += s[k]; tc += c[k]; }
#pragma unroll
        for (int off = 32; off > 0; off >>= 1) {
            ts += __shfl_down(ts, off);
            tc += __shfl_down(tc, off);
        }
        if (lane == 0) { lds[wid] = ts; lds[8 + wid] = tc; }
        __syncthreads();
        if (tid == 0) {
            double S = 0.0, C = 0.0;
#pragma unroll
            for (int w = 0; w < 8; ++w) { S += lds[w]; C += lds[8 + w]; }
            double Sm = S / (double)NT, Cm = C / (double)NT;
            ws_r[g] = sqrt(Sm * Sm + Cm * Cm);
        }
    }
#pragma unroll
    for (int k = 0; k < B_ELEMS; ++k) {
        int t = tid + k * B_THREADS;
        long idx = (long)g * NT + t;
        ws_s[idx] = (float)s[k]; ws_c[idx] = (float)c[k];               // for k_mask
        out_ph[((long)(l * NB + b) * NT + t) * NO + o] = (float)ph[k];  // (L,B,T,O)
    }
}

// ------------- Kernel C: windowed coherence -> boundary mask ----------------
__global__ __launch_bounds__(256) void k_mask(
    const float* __restrict__ ws_s, const float* __restrict__ ws_c,
    float* __restrict__ out_mask)
{
    const int bid = blockIdx.x;            // 24 lb * 16 t-slices
    const int lb = bid >> 4;               // l*NB + b
    const int t0 = ((bid & 15) << 8) + threadIdx.x;
    float* mrow = out_mask + (long)lb * (NT - 2);
    if ((bid & 15) == 0 && threadIdx.x < 2) mrow[threadIdx.x] = 0.0f;
    if (t0 >= NT - 4) return;
    double q[3] = {0.0, 0.0, 0.0};
#pragma unroll
    for (int o = 0; o < NO; ++o) {
        const float* ps = ws_s + ((long)lb * NO + o) * NT + t0;
        const float* pc = ws_c + ((long)lb * NO + o) * NT + t0;
        double sv[5], cv[5];
#pragma unroll
        for (int j = 0; j < 5; ++j) { sv[j] = (double)ps[j]; cv[j] = (double)pc[j]; }
#pragma unroll
        for (int j = 0; j < 3; ++j) {
            double ms = ((sv[j] + sv[j + 1]) + sv[j + 2]) / 3.0;
            double mc = ((cv[j] + cv[j + 1]) + cv[j + 2]) / 3.0;
            q[j] += sqrt(ms * ms + mc * mc);
        }
    }
    double coh0 = q[0] / 4.0, coh1 = q[1] / 4.0, coh2 = q[2] / 4.0;
    bool cond = (coh1 < coh0 - THRESH_D) && (coh1 < coh2 - THRESH_D);
    mrow[2 + t0] = cond ? 1.0f : 0.0f;
}

// ------------- Kernel D: level coherences (24 values) -----------------------
__global__ void k_level(const double* __restrict__ ws_r, float* __restrict__ out_lvl)
{
    const int tid = threadIdx.x;
    if (tid < NB * NL) {
        const int b = tid / NL, l = tid % NL;   // output is (B, L)
        const double* r = ws_r + (long)(l * NB + b) * NO;
        double m = (((r[0] + r[1]) + r[2]) + r[3]) / 4.0;
        out_lvl[tid] = (float)m;
    }
}

extern "C" void kernel_launch(void* const* d_in, const int* in_sizes, int n_in,
                              void* d_out, int out_size, void* d_ws, size_t ws_size,
                              hipStream_t stream)
{
    const float* x      = (const float*)d_in[0];
    const float* W      = (const float*)d_in[1];
    const float* omegas = (const float*)d_in[2];
    const float* Ks     = (const float*)d_in[3];
    float* out = (float*)d_out;

    double* wsWt    = (double*)d_ws;                   // 16384 f64 (128 KB)
    double* ws_proj = wsWt + 1024 * 16;                // 12*32768 f64 (3 MB)
    float*  ws_s    = (float*)(ws_proj + (long)NLO * NROWS);  // 393216 f32
    float*  ws_c    = ws_s + (long)NLO * NB * NT;             // 393216 f32
    double* ws_r    = (double*)(ws_c + (long)NLO * NB * NT);  // 96 f64

    float* out_ph   = out;            // 393216
    float* out_lvl  = out + 393216;   // 24
    float* out_mask = out + 393240;   // 98256

    k_wprep<<<64, 256, 0, stream>>>(W, wsWt);
    k_proj<<<NROWS / 32, 256, 0, stream>>>(x, wsWt, ws_proj);
    k_kuramoto<<<NL * NB * NO, B_THREADS, 0, stream>>>(omegas, Ks, ws_proj, ws_s, ws_c, ws_r, out_ph);
    k_mask<<<24 * 16, 256, 0, stream>>>(ws_s, ws_c, out_mask);
    k_level<<<1, 64, 0, stream>>>(ws_r, out_lvl);
}

// Round 15
// 65.755 us; speedup vs baseline: 1.0048x; 1.0048x over previous
//
#include <hip/hip_runtime.h>
#include <math.h>

#define NB 8
#define NT 4096
#define ND 1024
#define NL 3
#define NO 4
#define NLO 12
#define NROWS (NB * NT)          // 32768
#define TWO_PI_D 6.283185307179586476925286766559
#define DT_D 0.1
#define NSTEPS 10
#define THRESH_D 0.3

typedef double f64x4 __attribute__((ext_vector_type(4)));

// ------------- Kernel W-prep: W[12][1024] f32 -> Wt[1024][16] f64 (padded) --
__global__ __launch_bounds__(256) void k_wprep(const float* __restrict__ W,
                                               double* __restrict__ wsWt)
{
    int i = blockIdx.x * 256 + threadIdx.x;   // 0..16383
    if (i < 1024 * 16) {
        int k = i >> 4, col = i & 15;
        wsWt[i] = (col < NLO) ? (double)W[col * ND + k] : 0.0;
    }
}

// ------------- Kernel A v14: f64 MFMA GEMM, depth-2 register pipeline -------
// v13 structure (1024 blk x 4 waves, 2 row-tiles/wave, B amortized) with the
// pipeline deepened to 2: x loads issued 2 ss ahead (~1400 cyc to land),
// B loads 1 ss ahead (L2 ~200 cyc), ds_write's vmcnt wait is on loads issued
// a full period ago (~0 stall). Only remaining per-ss wait: lgkmcnt on 8
// conflict-free ds_read_b32. setprio around the MFMA cluster (independent
// waves). All pipeline state in named regs / constant-index arrays.
__global__ __launch_bounds__(256, 4) void k_proj(
    const float* __restrict__ x, const double* __restrict__ wsWt,
    double* __restrict__ ws_proj)
{
    __shared__ char buf[20480];                   // 4 waves x 2 halves x 32x20 f32
    const int tid  = threadIdx.x;
    const int lane = tid & 63;
    const int wid  = tid >> 6;                    // K-quarter 0..3
    const int m    = lane & 15;
    const int kk   = lane >> 4;                   // 0..3
    const long row0 = (long)blockIdx.x * 32;

    float* wtile = reinterpret_cast<float*>(buf) + wid * 1280;  // 2 halves x 640
    const int srow = lane >> 2;                   // staging row 0..15
    const int slot = lane & 3;
    const float* xg = x + (row0 + srow) * ND + wid * 256 + slot * 4;
    const double* wq = wsWt + (long)(wid * 256) * 16;

    f64x4 accA = {0.0, 0.0, 0.0, 0.0};
    f64x4 accB = {0.0, 0.0, 0.0, 0.0};

    // pipeline regs
    float4 frwA, frwB;        // x data for ss+1 (to ds_write this iter)
    float4 frlA, frlB;        // x data for ss+2 (being loaded)
    double bv[4], bn[4];      // B frags: current ss / next ss

    // prologue: x(0) -> half0; frw = x(1); bv = B(0)
    {
        float4 f0A = *reinterpret_cast<const float4*>(xg);
        float4 f0B = *reinterpret_cast<const float4*>(xg + 16 * ND);
        frwA = *reinterpret_cast<const float4*>(xg + 16);
        frwB = *reinterpret_cast<const float4*>(xg + 16 * ND + 16);
#pragma unroll
        for (int p = 0; p < 4; ++p) bv[p] = wq[(4 * p + kk) * 16 + m];
        *reinterpret_cast<float4*>(&wtile[srow * 20 + slot * 4]) = f0A;
        *reinterpret_cast<float4*>(&wtile[(16 + srow) * 20 + slot * 4]) = f0B;
    }

#pragma unroll 2
    for (int ss = 0; ss < 16; ++ss) {
        float* cur = wtile + (ss & 1) * 640;
        float* nxt = wtile + ((ss + 1) & 1) * 640;
        // (1) write x(ss+1) — issued a full period ago, near-zero vmcnt wait
        if (ss < 15) {
            *reinterpret_cast<float4*>(&nxt[srow * 20 + slot * 4]) = frwA;
            *reinterpret_cast<float4*>(&nxt[(16 + srow) * 20 + slot * 4]) = frwB;
        }
        // (2) issue x(ss+2)
        if (ss < 14) {
            frlA = *reinterpret_cast<const float4*>(xg + 16 * (ss + 2));
            frlB = *reinterpret_cast<const float4*>(xg + 16 * ND + 16 * (ss + 2));
        }
        // (3) issue B(ss+1)
        if (ss < 15) {
#pragma unroll
            for (int p = 0; p < 4; ++p)
                bn[p] = wq[(16 * (ss + 1) + 4 * p + kk) * 16 + m];
        }
        // (4) A frags from current half (2 lanes/bank = free) + 8 MFMA
        __builtin_amdgcn_s_setprio(1);
#pragma unroll
        for (int p = 0; p < 4; ++p) {
            double aA = (double)cur[m * 20 + 4 * p + kk];
            double aB = (double)cur[(16 + m) * 20 + 4 * p + kk];
            accA = __builtin_amdgcn_mfma_f64_16x16x4f64(aA, bv[p], accA, 0, 0, 0);
            accB = __builtin_amdgcn_mfma_f64_16x16x4f64(aB, bv[p], accB, 0, 0, 0);
        }
        __builtin_amdgcn_s_setprio(0);
        // (5) rotate pipeline regs (pure renames after unroll)
        frwA = frlA; frwB = frlB;
#pragma unroll
        for (int p = 0; p < 4; ++p) bv[p] = bn[p];
    }

    // inline C/D layout probe (separable inputs; same feed convention)
    f64x4 z = {0.0, 0.0, 0.0, 0.0};
    f64x4 d1 = __builtin_amdgcn_mfma_f64_16x16x4f64((double)m, 1.0, z, 0, 0, 0);
    f64x4 d2 = __builtin_amdgcn_mfma_f64_16x16x4f64(1.0, (double)m, z, 0, 0, 0);

    // 4-way K-fold through LDS (red overlays tiles; 16 KB <= 20 KB)
    __syncthreads();
    double* red = reinterpret_cast<double*>(buf);
#pragma unroll
    for (int n = 0; n < 4; ++n)
        red[((wid * 2 + 0) * 64 + lane) * 4 + n] = accA[n];
#pragma unroll
    for (int n = 0; n < 4; ++n)
        red[((wid * 2 + 1) * 64 + lane) * 4 + n] = accB[n];
    __syncthreads();

    if (wid < 2) {                                // thread folds tile t = wid
#pragma unroll
        for (int n = 0; n < 4; ++n) {
            double v = (red[((0 * 2 + wid) * 64 + lane) * 4 + n] +
                        red[((1 * 2 + wid) * 64 + lane) * 4 + n]) +
                       (red[((2 * 2 + wid) * 64 + lane) * 4 + n] +
                        red[((3 * 2 + wid) * 64 + lane) * 4 + n]);
            int i = (int)(d1[n] * 0.25 + 0.5);
            int j = (int)(d2[n] * 0.25 + 0.5);
            if (j < NLO)
                ws_proj[(long)j * NROWS + row0 + wid * 16 + i] = v;
        }
    }
}

// ------------- Kernel B v5: fused phase-init + 10 Kuramoto steps ------------
#define B_THREADS 512
#define B_ELEMS (NT / B_THREADS)   // 8

__global__ __launch_bounds__(B_THREADS) void k_kuramoto(
    const float* __restrict__ omegas, const float* __restrict__ Ks,
    const double* __restrict__ ws_proj, float* __restrict__ ws_s,
    float* __restrict__ ws_c, double* __restrict__ ws_r,
    float* __restrict__ out_ph)
{
    const int g = blockIdx.x;              // (l*NB + b)*NO + o
    const int l = g >> 5;
    const int b = (g >> 2) & 7;
    const int o = g & 3;
    const double om = (double)omegas[l * NO + o];
    const double Kv = (double)Ks[l];
    const double dtom = DT_D * om;
    const double cKT = DT_D * Kv / (double)NT;  // |eps| <= dt*K/T ~ 5e-5
    double sA, cA; sincos(dtom, &sA, &cA);
    const int tid = threadIdx.x;
    const int wid = tid >> 6;
    const int lane = tid & 63;
    __shared__ double lds[16];

    // fused phase init from proj columns (contiguous reads)
    const double* pA = ws_proj + (long)(l * NO + o) * NROWS + (long)b * NT;
    const double* pB = ws_proj + (long)(l * NO + ((o + 3) & 3)) * NROWS + (long)b * NT;

    double ph[B_ELEMS], s[B_ELEMS], c[B_ELEMS];
#pragma unroll
    for (int k = 0; k < B_ELEMS; ++k) {
        int t = tid + k * B_THREADS;
        double y = pA[t];
        double xx = pB[t] + 1e-8;
        double p = atan2(y, xx);
        if (p < 0.0) p += TWO_PI_D;
        ph[k] = p;
        double r2 = sqrt(y * y + xx * xx);
        if (r2 > 0.0) { s[k] = y / r2; c[k] = xx / r2; }
        else          { s[k] = 0.0;    c[k] = 1.0; }
    }

    for (int step = 0; step < NSTEPS; ++step) {
        double ts = 0.0, tc = 0.0;
#pragma unroll
        for (int k = 0; k < B_ELEMS; ++k) { ts += s[k]; tc += c[k]; }
#pragma unroll
        for (int off = 32; off > 0; off >>= 1) {
            ts += __shfl_down(ts, off);
            tc += __shfl_down(tc, off);
        }
        if (lane == 0) { lds[wid] = ts; lds[8 + wid] = tc; }
        __syncthreads();
        // every thread redundantly folds the 8 partials (no serial section)
        double S = 0.0, C = 0.0;
#pragma unroll
        for (int w = 0; w < 8; ++w) { S += lds[w]; C += lds[8 + w]; }
        double rr = sqrt(S * S + C * C);
        double sm, cm;
        if (rr > 0.0) { sm = S / rr; cm = C / rr; } else { sm = 0.0; cm = 1.0; }
#pragma unroll
        for (int k = 0; k < B_ELEMS; ++k) {
            double sv = sm * c[k] - cm * s[k];      // sin(mean - ph)
            double eps = cKT * sv;                  // |eps| <= ~5e-5
            double val = ph[k] + (dtom + eps);
            if (val >= TWO_PI_D) val -= TWO_PI_D;   // exact (Sterbenz)
            if (val < 0.0) val += TWO_PI_D;
            ph[k] = val;
            // rotate (s,c) by dtom+eps: sd = sA + cA*eps, cd = cA - sA*eps
            double sd = fma(cA, eps, sA);
            double cd = fma(-sA, eps, cA);
            double sn = fma(s[k], cd, c[k] * sd);
            double cn = fma(c[k], cd, -(s[k] * sd));
            s[k] = sn; c[k] = cn;
        }
        __syncthreads();               // protect lds before next step's writes
    }
    // level coherence from final s,c
    {
        double ts = 0.0, tc = 0.0;
#pragma unroll
        for (int k = 0; k < B_ELEMS; ++k) { ts += s[k]; tc += c[k]; }
#pragma unroll
        for (int off = 32; off > 0; off >>= 1) {
            ts += __shfl_down(ts, off);
            tc += __shfl_down(tc, off);
        }
        if (lane == 0) { lds[wid] = ts; lds[8 + wid] = tc; }
        __syncthreads();
        if (tid == 0) {
            double S = 0.0, C = 0.0;
#pragma unroll
            for (int w = 0; w < 8; ++w) { S += lds[w]; C += lds[8 + w]; }
            double Sm = S / (double)NT, Cm = C / (double)NT;
            ws_r[g] = sqrt(Sm * Sm + Cm * Cm);
        }
    }
#pragma unroll
    for (int k = 0; k < B_ELEMS; ++k) {
        int t = tid + k * B_THREADS;
        long idx = (long)g * NT + t;
        ws_s[idx] = (float)s[k]; ws_c[idx] = (float)c[k];               // for k_mask
        out_ph[((long)(l * NB + b) * NT + t) * NO + o] = (float)ph[k];  // (L,B,T,O)
    }
}

// ------------- Kernel C: windowed coherence -> boundary mask ----------------
__global__ __launch_bounds__(256) void k_mask(
    const float* __restrict__ ws_s, const float* __restrict__ ws_c,
    float* __restrict__ out_mask)
{
    const int bid = blockIdx.x;            // 24 lb * 16 t-slices
    const int lb = bid >> 4;               // l*NB + b
    const int t0 = ((bid & 15) << 8) + threadIdx.x;
    float* mrow = out_mask + (long)lb * (NT - 2);
    if ((bid & 15) == 0 && threadIdx.x < 2) mrow[threadIdx.x] = 0.0f;
    if (t0 >= NT - 4) return;
    double q[3] = {0.0, 0.0, 0.0};
#pragma unroll
    for (int o = 0; o < NO; ++o) {
        const float* ps = ws_s + ((long)lb * NO + o) * NT + t0;
        const float* pc = ws_c + ((long)lb * NO + o) * NT + t0;
        double sv[5], cv[5];
#pragma unroll
        for (int j = 0; j < 5; ++j) { sv[j] = (double)ps[j]; cv[j] = (double)pc[j]; }
#pragma unroll
        for (int j = 0; j < 3; ++j) {
            double ms = ((sv[j] + sv[j + 1]) + sv[j + 2]) / 3.0;
            double mc = ((cv[j] + cv[j + 1]) + cv[j + 2]) / 3.0;
            q[j] += sqrt(ms * ms + mc * mc);
        }
    }
    double coh0 = q[0] / 4.0, coh1 = q[1] / 4.0, coh2 = q[2] / 4.0;
    bool cond = (coh1 < coh0 - THRESH_D) && (coh1 < coh2 - THRESH_D);
    mrow[2 + t0] = cond ? 1.0f : 0.0f;
}

// ------------- Kernel D: level coherences (24 values) -----------------------
__global__ void k_level(const double* __restrict__ ws_r, float* __restrict__ out_lvl)
{
    const int tid = threadIdx.x;
    if (tid < NB * NL) {
        const int b = tid / NL, l = tid % NL;   // output is (B, L)
        const double* r = ws_r + (long)(l * NB + b) * NO;
        double m = (((r[0] + r[1]) + r[2]) + r[3]) / 4.0;
        out_lvl[tid] = (float)m;
    }
}

extern "C" void kernel_launch(void* const* d_in, const int* in_sizes, int n_in,
                              void* d_out, int out_size, void* d_ws, size_t ws_size,
                              hipStream_t stream)
{
    const float* x      = (const float*)d_in[0];
    const float* W      = (const float*)d_in[1];
    const float* omegas = (const float*)d_in[2];
    const float* Ks     = (const float*)d_in[3];
    float* out = (float*)d_out;

    double* wsWt    = (double*)d_ws;                   // 16384 f64 (128 KB)
    double* ws_proj = wsWt + 1024 * 16;                // 12*32768 f64 (3 MB)
    float*  ws_s    = (float*)(ws_proj + (long)NLO * NROWS);  // 393216 f32
    float*  ws_c    = ws_s + (long)NLO * NB * NT;             // 393216 f32
    double* ws_r    = (double*)(ws_c + (long)NLO * NB * NT);  // 96 f64

    float* out_ph   = out;            // 393216
    float* out_lvl  = out + 393216;   // 24
    float* out_mask = out + 393240;   // 98256

    k_wprep<<<64, 256, 0, stream>>>(W, wsWt);
    k_proj<<<NROWS / 32, 256, 0, stream>>>(x, wsWt, ws_proj);
    k_kuramoto<<<NL * NB * NO, B_THREADS, 0, stream>>>(omegas, Ks, ws_proj, ws_s, ws_c, ws_r, out_ph);
    k_mask<<<24 * 16, 256, 0, stream>>>(ws_s, ws_c, out_mask);
    k_level<<<1, 64, 0, stream>>>(ws_r, out_lvl);
}